// Round 12
// baseline (463.891 us; speedup 1.0000x reference)
//
#include <hip/hip_runtime.h>
#include <hip/hip_bf16.h>
#include <hip/hip_cooperative_groups.h>
#include <math.h>

namespace cg = cooperative_groups;

// DCNv1 fused, bf16-MFMA, round 12: single cooperative kernel, residency
// math fixed vs round 11 (which silently failed to launch: 39424 B LDS ->
// 1 block/CU under 64-KiB occupancy accounting -> 512 co-resident blocks
// impossible). Now: LDS 32512 B (compressed meta: ushort2 idx + bf16x4
// weights) and __launch_bounds__(512,4) (VGPR<=128) -> 2 blocks/CU.
// Launch return code checked; fallback = proven 3-kernel round-9 path.

constexpr int B  = 4;
constexpr int C  = 256;
constexpr int H  = 64;
constexpr int W  = 64;
constexpr int OC = 256;
constexpr int Ho = 64;
constexpr int Wo = 64;

constexpr int NT     = 64;   // positions per block (full wo row)
constexpr int CHUNKS = 72;   // 2304 / 32
constexpr int WROW   = 40;   // padded row (bf16): 80 B rows

constexpr size_t WA_ELTS  = (size_t)CHUNKS * OC * WROW;   // 737280 ushorts
constexpr size_t XB_ELTS  = (size_t)B * 8 * 4096 * 32;    // 4194304 ushorts
constexpr size_t OUT_ELTS = (size_t)B * OC * Ho * Wo;     // 4194304 floats

typedef __attribute__((ext_vector_type(8))) short bf16x8;
typedef __attribute__((ext_vector_type(4))) float f32x4;

__device__ __forceinline__ float bf_lo(unsigned u) {
    union { unsigned i; float f; } c; c.i = u << 16; return c.f;
}
__device__ __forceinline__ float bf_hi(unsigned u) {
    union { unsigned i; float f; } c; c.i = u & 0xffff0000u; return c.f;
}
__device__ __forceinline__ float bfu(ushort u) {
    union { unsigned i; float f; } c; c.i = (unsigned)u << 16; return c.f;
}
__device__ __forceinline__ ushort fbf(float f) {
    __hip_bfloat16 h = __float2bfloat16(f); return *(ushort*)&h;
}

// ===================== single cooperative kernel ===========================
__global__ __launch_bounds__(512, 4)   // 4 waves/EU = 2 blocks/CU @ 512 thr
void dcn_all(const float* __restrict__ x, const float* __restrict__ wt,
             const float* __restrict__ off, ushort* __restrict__ xb,
             ushort* __restrict__ wA, float* __restrict__ po,
             float* __restrict__ out)
{
    // 32512 B LDS, aliased per phase. 2 x 32512 = 65024 <= 65536.
    __shared__ __align__(16) unsigned char smem[32512];
    cg::grid_group grid = cg::this_grid();
    const int tid = threadIdx.x;                // 0..511

    // ================= Phase 1: prep (x transpose + w pack) ===============
    {
        const int half = tid >> 8, t = tid & 255;
        const int id  = blockIdx.x * 2 + half;  // 0..1023
        const int hwb = id & 31;
        const int cb  = (id >> 5) & 7;
        const int b   = id >> 8;
        const int hw0 = hwb << 7;
        const int lhw = t & 127, chalf = t >> 7;
        ushort* sx = (ushort*)smem + half * (128 * WROW);   // 2 x 10240 B
        #pragma unroll
        for (int i = 0; i < 16; ++i) {
            const int c = i * 2 + chalf;        // 0..31
            const float v = x[(((size_t)(b * 256 + cb * 32 + c)) << 12) + hw0 + lhw];
            sx[lhw * WROW + c] = fbf(v);
        }
        __syncthreads();
        const int whw = t >> 1, wh = t & 1;     // 4 uint4 per 64-B hw row
        const uint4 v0 = *(const uint4*)&sx[whw * WROW + wh * 16];
        const uint4 v1 = *(const uint4*)&sx[whw * WROW + wh * 16 + 8];
        uint4* dst = (uint4*)(xb + ((size_t)((b * 8 + cb) * 4096 + hw0) << 5));
        dst[whw * 4 + wh * 2 + 0] = v0;
        dst[whw * 4 + wh * 2 + 1] = v1;

        if (blockIdx.x < 256) {                 // w: one oc per block
            ushort* sw = (ushort*)(smem + 20480);           // 5760 B
            const int oc = blockIdx.x;
            if (tid < 256) {
                const int c = tid, chb = c >> 5, kk = c & 31;
                const float* wp = wt + ((size_t)oc * C + c) * 9;
                #pragma unroll
                for (int tap = 0; tap < 9; ++tap)
                    sw[(tap * 8 + chb) * WROW + kk] = fbf(wp[tap]);
                if (c < CHUNKS) {
                    #pragma unroll
                    for (int j = 0; j < 8; ++j) sw[c * WROW + 32 + j] = 0;
                }
            }
            __syncthreads();
            const uint4* sv = (const uint4*)sw;
            for (int i = tid; i < CHUNKS * 5; i += 512) {
                const int row = i / 5, q = i % 5;
                ((uint4*)(wA + ((size_t)row * OC + oc) * WROW))[q] = sv[i];
            }
        }
    }
    __threadfence();
    grid.sync();

    // ================= Phase 2: ksplit=2 MFMA main ========================
    {
        ushort*  s_wA  = (ushort*)smem;                  // 20480 B
        ushort*  s_col = (ushort*)(smem + 20480);        //  5120 B
        ushort2* s_mi  = (ushort2*)(smem + 25600);       //  2304 B
        ushort4* s_mw4 = (ushort4*)(smem + 27904);       //  4608 B  (bf16 x4)

        const int xcd = blockIdx.x & 7;
        const int ii  = blockIdx.x >> 3;            // 0..63
        const int b   = xcd & 3;
        const int khalf = ii & 1;
        const int ho  = ((xcd >> 2) << 5) + (ii >> 1);
        const int ch0 = khalf * 36, ch1 = ch0 + 36;
        float* outp = po + (size_t)khalf * OUT_ELTS;

        for (int s = tid; s < 9 * NT; s += 512) {
            const int n   = s & 63;
            const int tap = s >> 6;
            const float dy = off[((size_t)(b * 18 + 2 * tap)     * Ho + ho) * Wo + n];
            const float dx = off[((size_t)(b * 18 + 2 * tap + 1) * Ho + ho) * Wo + n];
            const float ph = (float)(ho - 1 + tap / 3) + dy;
            const float pw = (float)(n  - 1 + tap % 3) + dx;
            const float h0f = floorf(ph), w0f = floorf(pw);
            const int h0 = (int)h0f, w0 = (int)w0f;
            const float lh = ph - h0f, lw = pw - w0f;
            const int wb = min(max(w0, 0), W - 2);
            const int ht = min(max(h0, 0), H - 1);
            const int hb = min(max(h0 + 1, 0), H - 1);
            const float s0 = (wb == w0) ? (1.f - lw) : ((wb == w0 + 1) ? lw : 0.f);
            const float s1 = (wb + 1 == w0 + 1) ? lw : ((wb + 1 == w0) ? (1.f - lw) : 0.f);
            const float wtp = (h0 >= 0 && h0 < H)         ? (1.f - lh) : 0.f;
            const float wbt = (h0 + 1 >= 0 && h0 + 1 < H) ? lh         : 0.f;
            s_mi[s]  = make_ushort2((ushort)(ht * W + wb), (ushort)(hb * W + wb));
            s_mw4[s] = make_ushort4(fbf(wtp * s0), fbf(wtp * s1),
                                    fbf(wbt * s0), fbf(wbt * s1));
        }

        const int lane = tid & 63;
        const int wv   = tid >> 6;        // 0..7
        const int ocb  = wv >> 1;         // oc block of 64
        const int phh  = wv & 1;          // pos half of 32
        const int kq   = lane >> 4;
        const int mr   = lane & 15;
        const int sm_tid = tid - 256;
        const int sn  = sm_tid & 63;
        const int sgg = sm_tid >> 6;

        f32x4 acc[4][2];
        #pragma unroll
        for (int mt = 0; mt < 4; ++mt)
            #pragma unroll
            for (int nt = 0; nt < 2; ++nt)
                acc[mt][nt] = (f32x4){0.f, 0.f, 0.f, 0.f};

        for (int ch = ch0; ch < ch1; ++ch) {
            __syncthreads();

            if (tid < 256) {
                #pragma unroll
                for (int i = 0; i < 5; ++i) {
                    const int seg = wv * 5 + i;            // wave-uniform
                    __builtin_amdgcn_global_load_lds(
                        (const __attribute__((address_space(1))) void*)
                            (wA + (size_t)ch * OC * WROW + seg * 512 + lane * 8),
                        (__attribute__((address_space(3))) void*)&s_wA[seg * 512],
                        16, 0, 0);
                }
            } else {
                const int tap = ch >> 3;
                const int cb  = ch & 7;
                const ushort2 mi  = s_mi[tap * NT + sn];
                const ushort4 mwp = s_mw4[tap * NT + sn];
                const float w00 = bfu(mwp.x), w01 = bfu(mwp.y);
                const float w10 = bfu(mwp.z), w11 = bfu(mwp.w);
                const ushort* xp = xb + ((size_t)(b * 8 + cb) << 17) + (sgg << 3);
                const uint4 c00 = *(const uint4*)(xp + ((size_t)mi.x << 5));
                const uint4 c01 = *(const uint4*)(xp + (((size_t)mi.x + 1) << 5));
                const uint4 c10 = *(const uint4*)(xp + ((size_t)mi.y << 5));
                const uint4 c11 = *(const uint4*)(xp + (((size_t)mi.y + 1) << 5));
                union { ushort pk[8]; uint4 v; } u;
                const unsigned a00[4] = {c00.x, c00.y, c00.z, c00.w};
                const unsigned a01[4] = {c01.x, c01.y, c01.z, c01.w};
                const unsigned a10[4] = {c10.x, c10.y, c10.z, c10.w};
                const unsigned a11[4] = {c11.x, c11.y, c11.z, c11.w};
                #pragma unroll
                for (int j = 0; j < 4; ++j) {
                    const float vlo = w00 * bf_lo(a00[j]) + w01 * bf_lo(a01[j])
                                    + w10 * bf_lo(a10[j]) + w11 * bf_lo(a11[j]);
                    const float vhi = w00 * bf_hi(a00[j]) + w01 * bf_hi(a01[j])
                                    + w10 * bf_hi(a10[j]) + w11 * bf_hi(a11[j]);
                    u.pk[2 * j]     = fbf(vlo);
                    u.pk[2 * j + 1] = fbf(vhi);
                }
                *(uint4*)&s_col[sn * WROW + sgg * 8] = u.v;
            }
            __syncthreads();   // drains global_load_lds DMAs (vmcnt) too

            bf16x8 bfr[2];
            #pragma unroll
            for (int nt = 0; nt < 2; ++nt)
                bfr[nt] = *(const bf16x8*)&s_col[((phh * 2 + nt) * 16 + mr) * WROW + kq * 8];
            #pragma unroll
            for (int mt = 0; mt < 4; ++mt) {
                const bf16x8 afr = *(const bf16x8*)&s_wA[(ocb * 64 + mt * 16 + mr) * WROW + kq * 8];
                #pragma unroll
                for (int nt = 0; nt < 2; ++nt)
                    acc[mt][nt] = __builtin_amdgcn_mfma_f32_16x16x32_bf16(afr, bfr[nt], acc[mt][nt], 0, 0, 0);
            }
        }

        #pragma unroll
        for (int mt = 0; mt < 4; ++mt)
            #pragma unroll
            for (int nt = 0; nt < 2; ++nt)
                #pragma unroll
                for (int r = 0; r < 4; ++r) {
                    const int oc = ocb * 64 + mt * 16 + kq * 4 + r;
                    const int wo = (phh * 2 + nt) * 16 + mr;
                    outp[((size_t)(b * OC + oc) * Ho + ho) * Wo + wo] = acc[mt][nt][r];
                }
    }
    __threadfence();
    grid.sync();

    // ================= Phase 3: reduce out = p0 + p1 ======================
    {
        const float4* p0 = (const float4*)po;
        const float4* p1 = (const float4*)(po + OUT_ELTS);
        float4* o4 = (float4*)out;
        const int nf4 = (int)(OUT_ELTS / 4);              // 1048576
        for (int i = blockIdx.x * 512 + tid; i < nf4; i += 512 * 512) {
            const float4 a = p0[i], c = p1[i];
            o4[i] = make_float4(a.x + c.x, a.y + c.y, a.z + c.z, a.w + c.w);
        }
    }
}

// ===================== fallback: proven round-9 3-kernel path ==============
__global__ __launch_bounds__(256)
void prep_all_fb(const float* __restrict__ x, const float* __restrict__ wt,
                 ushort* __restrict__ xb, ushort* __restrict__ wA)
{
    __shared__ ushort sx[128 * WROW];
    __shared__ ushort sw[CHUNKS * WROW];
    const int t = threadIdx.x;
    if (blockIdx.x < 1024) {
        const int blk = blockIdx.x;
        const int hwb = blk & 31;
        const int cb  = (blk >> 5) & 7;
        const int b   = blk >> 8;
        const int hw0 = hwb << 7;
        const int lhw = t & 127, chalf = t >> 7;
        #pragma unroll
        for (int i = 0; i < 16; ++i) {
            const int c = i * 2 + chalf;
            sx[lhw * WROW + c] = fbf(x[(((size_t)(b * 256 + cb * 32 + c)) << 12) + hw0 + lhw]);
        }
        __syncthreads();
        const int whw = t >> 1, wh = t & 1;
        const uint4 v0 = *(const uint4*)&sx[whw * WROW + wh * 16];
        const uint4 v1 = *(const uint4*)&sx[whw * WROW + wh * 16 + 8];
        uint4* dst = (uint4*)(xb + ((size_t)((b * 8 + cb) * 4096 + hw0) << 5));
        dst[whw * 4 + wh * 2 + 0] = v0;
        dst[whw * 4 + wh * 2 + 1] = v1;
    } else {
        const int oc = blockIdx.x - 1024;
        const int c  = t, chb = c >> 5, kk = c & 31;
        const float* wp = wt + ((size_t)oc * C + c) * 9;
        #pragma unroll
        for (int tap = 0; tap < 9; ++tap)
            sw[(tap * 8 + chb) * WROW + kk] = fbf(wp[tap]);
        if (c < CHUNKS) {
            #pragma unroll
            for (int j = 0; j < 8; ++j) sw[c * WROW + 32 + j] = 0;
        }
        __syncthreads();
        const uint4* sv = (const uint4*)sw;
        for (int i = c; i < CHUNKS * 5; i += 256) {
            const int row = i / 5, q = i % 5;
            ((uint4*)(wA + ((size_t)row * OC + oc) * WROW))[q] = sv[i];
        }
    }
}

__global__ __launch_bounds__(512, 1)
void dcn_mfma_fb(const ushort* __restrict__ xb, const float* __restrict__ off,
                 const ushort* __restrict__ wA_g, float* __restrict__ po)
{
    __shared__ __align__(16) ushort s_wA[OC * WROW];
    __shared__ __align__(16) ushort s_col[NT * WROW];
    __shared__ int2   s_midx[9 * NT];
    __shared__ float4 s_mw[9 * NT];

    const int xcd = blockIdx.x & 7;
    const int ii  = blockIdx.x >> 3;
    const int b   = xcd & 3;
    const int khalf = ii & 1;
    const int ho  = ((xcd >> 2) << 5) + (ii >> 1);
    const int ch0 = khalf * 36, ch1 = ch0 + 36;
    float* outp = po + (size_t)khalf * OUT_ELTS;
    const int tid = threadIdx.x;

    for (int s = tid; s < 9 * NT; s += 512) {
        const int n   = s & 63;
        const int tap = s >> 6;
        const float dy = off[((size_t)(b * 18 + 2 * tap)     * Ho + ho) * Wo + n];
        const float dx = off[((size_t)(b * 18 + 2 * tap + 1) * Ho + ho) * Wo + n];
        const float ph = (float)(ho - 1 + tap / 3) + dy;
        const float pw = (float)(n  - 1 + tap % 3) + dx;
        const float h0f = floorf(ph), w0f = floorf(pw);
        const int h0 = (int)h0f, w0 = (int)w0f;
        const float lh = ph - h0f, lw = pw - w0f;
        const int wb = min(max(w0, 0), W - 2);
        const int ht = min(max(h0, 0), H - 1);
        const int hb = min(max(h0 + 1, 0), H - 1);
        const float s0 = (wb == w0) ? (1.f - lw) : ((wb == w0 + 1) ? lw : 0.f);
        const float s1 = (wb + 1 == w0 + 1) ? lw : ((wb + 1 == w0) ? (1.f - lw) : 0.f);
        const float wtp = (h0 >= 0 && h0 < H)         ? (1.f - lh) : 0.f;
        const float wbt = (h0 + 1 >= 0 && h0 + 1 < H) ? lh         : 0.f;
        s_midx[s] = make_int2(ht * W + wb, hb * W + wb);
        s_mw[s]   = make_float4(wtp * s0, wtp * s1, wbt * s0, wbt * s1);
    }

    const int lane = tid & 63;
    const int wv   = tid >> 6;
    const int ocb  = wv >> 1;
    const int phh  = wv & 1;
    const int kq   = lane >> 4;
    const int mr   = lane & 15;
    const int sm_tid = tid - 256;
    const int sn  = sm_tid & 63;
    const int sgg = sm_tid >> 6;

    f32x4 acc[4][2];
    #pragma unroll
    for (int mt = 0; mt < 4; ++mt)
        #pragma unroll
        for (int nt = 0; nt < 2; ++nt)
            acc[mt][nt] = (f32x4){0.f, 0.f, 0.f, 0.f};

    for (int ch = ch0; ch < ch1; ++ch) {
        __syncthreads();
        if (tid < 256) {
            #pragma unroll
            for (int i = 0; i < 5; ++i) {
                const int seg = wv * 5 + i;
                __builtin_amdgcn_global_load_lds(
                    (const __attribute__((address_space(1))) void*)
                        (wA_g + (size_t)ch * OC * WROW + seg * 512 + lane * 8),
                    (__attribute__((address_space(3))) void*)&s_wA[seg * 512],
                    16, 0, 0);
            }
        } else {
            const int tap = ch >> 3;
            const int cb  = ch & 7;
            const int2   mi = s_midx[tap * NT + sn];
            const float4 mw = s_mw[tap * NT + sn];
            const ushort* xp = xb + ((size_t)(b * 8 + cb) << 17) + (sgg << 3);
            const uint4 c00 = *(const uint4*)(xp + ((size_t)mi.x << 5));
            const uint4 c01 = *(const uint4*)(xp + (((size_t)mi.x + 1) << 5));
            const uint4 c10 = *(const uint4*)(xp + ((size_t)mi.y << 5));
            const uint4 c11 = *(const uint4*)(xp + (((size_t)mi.y + 1) << 5));
            union { ushort pk[8]; uint4 v; } u;
            const unsigned a00[4] = {c00.x, c00.y, c00.z, c00.w};
            const unsigned a01[4] = {c01.x, c01.y, c01.z, c01.w};
            const unsigned a10[4] = {c10.x, c10.y, c10.z, c10.w};
            const unsigned a11[4] = {c11.x, c11.y, c11.z, c11.w};
            #pragma unroll
            for (int j = 0; j < 4; ++j) {
                const float vlo = mw.x * bf_lo(a00[j]) + mw.y * bf_lo(a01[j])
                                + mw.z * bf_lo(a10[j]) + mw.w * bf_lo(a11[j]);
                const float vhi = mw.x * bf_hi(a00[j]) + mw.y * bf_hi(a01[j])
                                + mw.z * bf_hi(a10[j]) + mw.w * bf_hi(a11[j]);
                u.pk[2 * j]     = fbf(vlo);
                u.pk[2 * j + 1] = fbf(vhi);
            }
            *(uint4*)&s_col[sn * WROW + sgg * 8] = u.v;
        }
        __syncthreads();

        bf16x8 bfr[2];
        #pragma unroll
        for (int nt = 0; nt < 2; ++nt)
            bfr[nt] = *(const bf16x8*)&s_col[((phh * 2 + nt) * 16 + mr) * WROW + kq * 8];
        #pragma unroll
        for (int mt = 0; mt < 4; ++mt) {
            const bf16x8 afr = *(const bf16x8*)&s_wA[(ocb * 64 + mt * 16 + mr) * WROW + kq * 8];
            #pragma unroll
            for (int nt = 0; nt < 2; ++nt)
                acc[mt][nt] = __builtin_amdgcn_mfma_f32_16x16x32_bf16(afr, bfr[nt], acc[mt][nt], 0, 0, 0);
        }
    }

    #pragma unroll
    for (int mt = 0; mt < 4; ++mt)
        #pragma unroll
        for (int nt = 0; nt < 2; ++nt)
            #pragma unroll
            for (int r = 0; r < 4; ++r) {
                const int oc = ocb * 64 + mt * 16 + kq * 4 + r;
                const int wo = (phh * 2 + nt) * 16 + mr;
                outp[((size_t)(b * OC + oc) * Ho + ho) * Wo + wo] = acc[mt][nt][r];
            }
}

__global__ __launch_bounds__(256)
void reduce2_fb(const float4* __restrict__ p0, const float4* __restrict__ p1,
                float4* __restrict__ out)
{
    const int i = blockIdx.x * 256 + threadIdx.x;
    const float4 a = p0[i], b = p1[i];
    out[i] = make_float4(a.x + b.x, a.y + b.y, a.z + b.z, a.w + b.w);
}

extern "C" void kernel_launch(void* const* d_in, const int* in_sizes, int n_in,
                              void* d_out, int out_size, void* d_ws, size_t ws_size,
                              hipStream_t stream)
{
    const float* x   = (const float*)d_in[0];
    const float* off = (const float*)d_in[1];
    const float* wt  = (const float*)d_in[2];
    float* out = (float*)d_out;

    ushort* wA = (ushort*)d_ws;                 // 1.47 MB
    ushort* xb = wA + WA_ELTS;                  // 8.39 MB
    float*  po = (float*)(xb + XB_ELTS);        // 2 x 16.78 MB partials

    void* args[] = { (void*)&x, (void*)&wt, (void*)&off,
                     (void*)&xb, (void*)&wA, (void*)&po, (void*)&out };
    hipError_t err = hipLaunchCooperativeKernel((const void*)dcn_all,
                                                dim3(512), dim3(512),
                                                args, 0, stream);
    if (err != hipSuccess) {
        (void)hipGetLastError();   // clear sticky error, take proven path
        prep_all_fb<<<1280, 256, 0, stream>>>(x, wt, xb, wA);
        dcn_mfma_fb<<<512, 512, 0, stream>>>(xb, off, wA, po);
        reduce2_fb<<<(int)(OUT_ELTS / 4 / 256), 256, 0, stream>>>(
            (const float4*)po, (const float4*)(po + OUT_ELTS), (float4*)out);
    }
}

// Round 13
// 121.822 us; speedup vs baseline: 3.8079x; 3.8079x over previous
//
#include <hip/hip_runtime.h>
#include <hip/hip_bf16.h>
#include <math.h>

// DCNv1 fused, bf16-MFMA, round 13: round-9 3-kernel structure (cooperative
// single-kernel from r11/r12 abandoned: 394us, uniform 7.6x dilation).
// ONE change vs round 9: sampling lane map sn=sm_tid>>2, sgg=sm_tid&3 so the
// four 16-B quarters of each 64-B xb row are read by ADJACENT LANES of one
// wave -> each corner-gather instruction coalesces 4 lanes/line: sampling
// line-transactions drop 4x (1024 -> 256 per block-chunk). Attacks the
// ~1/cyc L1 addresser floor that r9's 1733 cyc/chunk-instance matches.

constexpr int B  = 4;
constexpr int C  = 256;
constexpr int H  = 64;
constexpr int W  = 64;
constexpr int OC = 256;
constexpr int Ho = 64;
constexpr int Wo = 64;

constexpr int NT     = 64;   // positions per block (full wo row)
constexpr int CHUNKS = 72;   // 2304 / 32
constexpr int WROW   = 40;   // padded row (bf16): 80 B rows

constexpr size_t WA_ELTS  = (size_t)CHUNKS * OC * WROW;   // 737280 ushorts
constexpr size_t XB_ELTS  = (size_t)B * 8 * 4096 * 32;    // 4194304 ushorts
constexpr size_t OUT_ELTS = (size_t)B * OC * Ho * Wo;     // 4194304 floats

typedef __attribute__((ext_vector_type(8))) short bf16x8;
typedef __attribute__((ext_vector_type(4))) float f32x4;

__device__ __forceinline__ float bf_lo(unsigned u) {
    union { unsigned i; float f; } c; c.i = u << 16; return c.f;
}
__device__ __forceinline__ float bf_hi(unsigned u) {
    union { unsigned i; float f; } c; c.i = u & 0xffff0000u; return c.f;
}
__device__ __forceinline__ ushort fbf(float f) {
    __hip_bfloat16 h = __float2bfloat16(f); return *(ushort*)&h;
}

// ---- fused pre-pass: blocks 0..1023 transpose x, blocks 1024..1279 do w ----
__global__ __launch_bounds__(256)
void prep_all(const float* __restrict__ x, const float* __restrict__ wt,
              ushort* __restrict__ xb, ushort* __restrict__ wA)
{
    __shared__ ushort sx[128 * WROW];         // x path: [hw][40]
    __shared__ ushort sw[CHUNKS * WROW];      // w path: [ch][40]
    const int t = threadIdx.x;

    if (blockIdx.x < 1024) {
        // ---- x: fp32 NCHW -> bf16 [b][cb][hw][c32] ----
        const int blk = blockIdx.x;           // (b*8+cb)*32 + hwb
        const int hwb = blk & 31;
        const int cb  = (blk >> 5) & 7;
        const int b   = blk >> 8;
        const int hw0 = hwb << 7;
        const int lhw = t & 127, chalf = t >> 7;
        #pragma unroll
        for (int i = 0; i < 16; ++i) {
            const int c = i * 2 + chalf;      // 0..31
            sx[lhw * WROW + c] =
                fbf(x[(((size_t)(b * 256 + cb * 32 + c)) << 12) + hw0 + lhw]);
        }
        __syncthreads();
        const int whw = t >> 1, wh = t & 1;   // 4 uint4 per 64-B hw row
        const uint4 v0 = *(const uint4*)&sx[whw * WROW + wh * 16];
        const uint4 v1 = *(const uint4*)&sx[whw * WROW + wh * 16 + 8];
        uint4* dst = (uint4*)(xb + ((size_t)((b * 8 + cb) * 4096 + hw0) << 5));
        dst[whw * 4 + wh * 2 + 0] = v0;
        dst[whw * 4 + wh * 2 + 1] = v1;
    } else {
        // ---- w: fp32 [oc][c][tap] -> bf16 wA[ch][oc][40] ----
        const int oc = blockIdx.x - 1024;
        const int c  = t, chb = c >> 5, kk = c & 31;
        const float* wp = wt + ((size_t)oc * C + c) * 9;
        #pragma unroll
        for (int tap = 0; tap < 9; ++tap)
            sw[(tap * 8 + chb) * WROW + kk] = fbf(wp[tap]);
        if (c < CHUNKS) {
            #pragma unroll
            for (int j = 0; j < 8; ++j) sw[c * WROW + 32 + j] = 0;
        }
        __syncthreads();
        const uint4* sv = (const uint4*)sw;
        for (int i = c; i < CHUNKS * 5; i += 256) {
            const int row = i / 5, q = i % 5;
            ((uint4*)(wA + ((size_t)row * OC + oc) * WROW))[q] = sv[i];
        }
    }
}

// ---------------- main fused kernel ----------------------------------------
__global__ __launch_bounds__(512, 1)
void dcn_mfma(const ushort* __restrict__ xb, const float* __restrict__ off,
              const ushort* __restrict__ wA_g, float* __restrict__ po)
{
    __shared__ __align__(16) ushort s_wA[OC * WROW];   // 20480 B
    __shared__ __align__(16) ushort s_col[NT * WROW];  //  5120 B
    __shared__ int2   s_midx[9 * NT];                  //  4608 B
    __shared__ float4 s_mw[9 * NT];                    //  9216 B

    // XCD swizzle: same b / ho-half (both khalves of a (b,ho)) per XCD.
    const int xcd = blockIdx.x & 7;
    const int ii  = blockIdx.x >> 3;            // 0..63
    const int b   = xcd & 3;
    const int khalf = ii & 1;
    const int ho  = ((xcd >> 2) << 5) + (ii >> 1);
    const int ch0 = khalf * 36, ch1 = ch0 + 36;
    float* outp = po + (size_t)khalf * OUT_ELTS;
    const int tid = threadIdx.x;

    // ---- Phase A: bilinear meta per (tap, n); zero-fold padding into wts ----
    for (int s = tid; s < 9 * NT; s += 512) {
        const int n   = s & 63;
        const int tap = s >> 6;
        const float dy = off[((size_t)(b * 18 + 2 * tap)     * Ho + ho) * Wo + n];
        const float dx = off[((size_t)(b * 18 + 2 * tap + 1) * Ho + ho) * Wo + n];
        const float ph = (float)(ho - 1 + tap / 3) + dy;
        const float pw = (float)(n  - 1 + tap % 3) + dx;
        const float h0f = floorf(ph), w0f = floorf(pw);
        const int h0 = (int)h0f, w0 = (int)w0f;
        const float lh = ph - h0f, lw = pw - w0f;
        const int wb = min(max(w0, 0), W - 2);      // pair base stays in-plane
        const int ht = min(max(h0, 0), H - 1);
        const int hb = min(max(h0 + 1, 0), H - 1);
        const float s0 = (wb == w0) ? (1.f - lw) : ((wb == w0 + 1) ? lw : 0.f);
        const float s1 = (wb + 1 == w0 + 1) ? lw : ((wb + 1 == w0) ? (1.f - lw) : 0.f);
        const float wtp = (h0 >= 0 && h0 < H)         ? (1.f - lh) : 0.f;
        const float wbt = (h0 + 1 >= 0 && h0 + 1 < H) ? lh         : 0.f;
        s_midx[s] = make_int2(ht * W + wb, hb * W + wb);
        s_mw[s]   = make_float4(wtp * s0, wtp * s1, wbt * s0, wbt * s1);
    }

    const int lane = tid & 63;
    const int wv   = tid >> 6;        // 0..7
    const int ocb  = wv >> 1;         // oc block of 64
    const int phh  = wv & 1;          // pos half of 32
    const int kq   = lane >> 4;
    const int mr   = lane & 15;

    // sampling lane map (THE r13 change): adjacent lanes take the 4 quarters
    // of one 64-B row -> corner gathers coalesce 4 lanes/line.
    const int sm_tid = tid - 256;     // 0..255 valid when tid >= 256
    const int sn  = sm_tid >> 2;      // position 0..63
    const int sgg = sm_tid & 3;       // channel octet 0..3

    f32x4 acc[4][2];
    #pragma unroll
    for (int mt = 0; mt < 4; ++mt)
        #pragma unroll
        for (int nt = 0; nt < 2; ++nt)
            acc[mt][nt] = (f32x4){0.f, 0.f, 0.f, 0.f};

    for (int ch = ch0; ch < ch1; ++ch) {
        __syncthreads();   // prior chunk's MFMA reads done before overwrite

        if (tid < 256) {
            // ---- weights -> LDS via direct DMA, identity-copy layout ----
            #pragma unroll
            for (int i = 0; i < 5; ++i) {
                const int seg = wv * 5 + i;            // wave-uniform
                __builtin_amdgcn_global_load_lds(
                    (const __attribute__((address_space(1))) void*)
                        (wA_g + (size_t)ch * OC * WROW + seg * 512 + lane * 8),
                    (__attribute__((address_space(3))) void*)&s_wA[seg * 512],
                    16, 0, 0);
            }
        } else {
            // ---- sample: 4 corners x 8 bf16 channels, ONE dwordx4 each ----
            const int tap = ch >> 3;
            const int cb  = ch & 7;
            const int2   mi = s_midx[tap * NT + sn];   // broadcast (4 lanes)
            const float4 mw = s_mw[tap * NT + sn];
            const ushort* xp = xb + ((size_t)(b * 8 + cb) << 17) + (sgg << 3);
            const uint4 c00 = *(const uint4*)(xp + ((size_t)mi.x << 5));
            const uint4 c01 = *(const uint4*)(xp + (((size_t)mi.x + 1) << 5));
            const uint4 c10 = *(const uint4*)(xp + ((size_t)mi.y << 5));
            const uint4 c11 = *(const uint4*)(xp + (((size_t)mi.y + 1) << 5));
            union { ushort pk[8]; uint4 v; } u;
            const unsigned a00[4] = {c00.x, c00.y, c00.z, c00.w};
            const unsigned a01[4] = {c01.x, c01.y, c01.z, c01.w};
            const unsigned a10[4] = {c10.x, c10.y, c10.z, c10.w};
            const unsigned a11[4] = {c11.x, c11.y, c11.z, c11.w};
            #pragma unroll
            for (int j = 0; j < 4; ++j) {
                const float vlo = mw.x * bf_lo(a00[j]) + mw.y * bf_lo(a01[j])
                                + mw.z * bf_lo(a10[j]) + mw.w * bf_lo(a11[j]);
                const float vhi = mw.x * bf_hi(a00[j]) + mw.y * bf_hi(a01[j])
                                + mw.z * bf_hi(a10[j]) + mw.w * bf_hi(a11[j]);
                u.pk[2 * j]     = fbf(vlo);
                u.pk[2 * j + 1] = fbf(vhi);
            }
            *(uint4*)&s_col[sn * WROW + sgg * 8] = u.v;
        }
        __syncthreads();   // drains global_load_lds DMAs (vmcnt) too

        // ---- MFMA: 4 M-tiles x 2 N-tiles per wave ----
        bf16x8 bfr[2];
        #pragma unroll
        for (int nt = 0; nt < 2; ++nt)
            bfr[nt] = *(const bf16x8*)&s_col[((phh * 2 + nt) * 16 + mr) * WROW + kq * 8];
        #pragma unroll
        for (int mt = 0; mt < 4; ++mt) {
            const bf16x8 afr = *(const bf16x8*)&s_wA[(ocb * 64 + mt * 16 + mr) * WROW + kq * 8];
            #pragma unroll
            for (int nt = 0; nt < 2; ++nt)
                acc[mt][nt] = __builtin_amdgcn_mfma_f32_16x16x32_bf16(afr, bfr[nt], acc[mt][nt], 0, 0, 0);
        }
    }

    // ---- epilogue: C/D layout col = lane&15 (pos), row = kq*4 + r (oc) ----
    #pragma unroll
    for (int mt = 0; mt < 4; ++mt)
        #pragma unroll
        for (int nt = 0; nt < 2; ++nt)
            #pragma unroll
            for (int r = 0; r < 4; ++r) {
                const int oc = ocb * 64 + mt * 16 + kq * 4 + r;
                const int wo = (phh * 2 + nt) * 16 + mr;
                outp[((size_t)(b * OC + oc) * Ho + ho) * Wo + wo] = acc[mt][nt][r];
            }
}

// ---- reduce: out = p0 + p1 (float4) ---------------------------------------
__global__ __launch_bounds__(256)
void reduce2(const float4* __restrict__ p0, const float4* __restrict__ p1,
             float4* __restrict__ out)
{
    const int i = blockIdx.x * 256 + threadIdx.x;   // over OUT_ELTS/4
    const float4 a = p0[i], b = p1[i];
    out[i] = make_float4(a.x + b.x, a.y + b.y, a.z + b.z, a.w + b.w);
}

extern "C" void kernel_launch(void* const* d_in, const int* in_sizes, int n_in,
                              void* d_out, int out_size, void* d_ws, size_t ws_size,
                              hipStream_t stream)
{
    const float* x   = (const float*)d_in[0];
    const float* off = (const float*)d_in[1];
    const float* wt  = (const float*)d_in[2];
    float* out = (float*)d_out;

    ushort* wA = (ushort*)d_ws;                 // 1.47 MB
    ushort* xb = wA + WA_ELTS;                  // 8.39 MB
    float*  po = (float*)(xb + XB_ELTS);        // 2 x 16.78 MB partials

    prep_all<<<1280, 256, 0, stream>>>(x, wt, xb, wA);
    dcn_mfma<<<512, 512, 0, stream>>>(xb, off, wA, po);
    reduce2<<<(int)(OUT_ELTS / 4 / 256), 256, 0, stream>>>(
        (const float4*)po, (const float4*)(po + OUT_ELTS), (float4*)out);
}